// Round 5
// baseline (960.329 us; speedup 1.0000x reference)
//
#include <hip/hip_runtime.h>
#include <math.h>

#define PRIME_Y 2654435761u

struct LevelParams { float scale; unsigned res; unsigned size; unsigned offset; };
struct EncParams { LevelParams lv[16]; };

typedef float v2f __attribute__((ext_vector_type(2)));

struct alignas(8) F2 { float x, y; };

// 4 threads per point, one per bilinear plane corner; quad shfl_xor reduce.
// R3 lesson: no min-waves clause -- __launch_bounds__(256,4) caused a 1.9 GB
// scratch spill. R4 lesson: weights stay in the scalar path (uniform global
// reads -> s_load), no LDS. R5: all FMA streams packed to float2 so the
// backend emits v_pk_fma_f32 (2x fp32 rate on gfx950); layer-2 runs over j
// in pairs so the w1 pair is one consecutive s_load_dwordx2.
__global__ __launch_bounds__(256) void plane_fwd(
    const F2* __restrict__ xy,
    const F2* __restrict__ table,
    const float* __restrict__ w0g,
    const float* __restrict__ w1g,
    const int* __restrict__ boundp,
    float* __restrict__ out,
    EncParams P)
{
  const int t = threadIdx.x;
  const int gid = blockIdx.x * 256 + t;
  const int p = gid >> 2;        // point index
  const int c = t & 3;           // corner: bit0 = x side, bit1 = y side
  F2 pxy = xy[p];

  int braw = boundp[0];
  float bf = (braw > 0x00800000) ? __int_as_float(braw) : (float)braw;
  float inv2b = 0.5f / bf;
  float xn = (pxy.x + bf) * inv2b;
  float yn = (pxy.y + bf) * inv2b;

  float cx  = fminf(fmaxf(xn * 2048.0f - 0.5f, 0.0f), 2047.0f);
  float cyv = fminf(fmaxf(yn * 2048.0f - 0.5f, 0.0f), 2047.0f);
  float cx0 = floorf(cx), cy0 = floorf(cyv);
  float u = cx - cx0, v = cyv - cy0;
  float cx1 = fminf(cx0 + 1.0f, 2047.0f);
  float cy1 = fminf(cy0 + 1.0f, 2047.0f);

  const float cxc = (c & 1) ? cx1 : cx0;
  const float cyc = (c & 2) ? cy1 : cy0;
  const float wc = ((c & 1) ? u : 1.0f - u) * ((c & 2) ? v : 1.0f - v);

  const float K = 1.0f / 2048.0f;
  const float gx = (cxc + 0.5f) * K;
  const float gy = (cyc + 0.5f) * K;

  v2f f2[16];

  #pragma unroll
  for (int l = 0; l < 16; ++l) {
    const float scale   = P.lv[l].scale;
    const unsigned res  = P.lv[l].res;
    const unsigned size = P.lv[l].size;
    const unsigned off  = P.lv[l].offset;
    const bool hashed = (res * res) > size;  // wave-uniform

    float px = fmaf(gx, scale, 0.5f);
    float pgx = floorf(px);
    float frx = px - pgx;
    unsigned ux = (unsigned)pgx;

    float py = fmaf(gy, scale, 0.5f);
    float pgy = floorf(py);
    float fry = py - pgy;
    unsigned uy = (unsigned)pgy;

    unsigned i00, i01, i10, i11;
    if (hashed) {
      const unsigned m = size - 1u;   // hashed levels: size == 2^19
      unsigned hy0 = uy * PRIME_Y;
      unsigned hy1 = (uy + 1u) * PRIME_Y;
      i00 = (ux ^ hy0) & m;
      i01 = (ux ^ hy1) & m;
      i10 = ((ux + 1u) ^ hy0) & m;
      i11 = ((ux + 1u) ^ hy1) & m;
    } else {
      unsigned b0 = uy * res, b1 = b0 + res;
      unsigned v00 = ux + b0,      v01 = ux + b1;
      unsigned v10 = ux + 1u + b0, v11 = ux + 1u + b1;
      // max index = res*res + res < 2*size, one cond-sub == mod
      i00 = v00 >= size ? v00 - size : v00;
      i01 = v01 >= size ? v01 - size : v01;
      i10 = v10 >= size ? v10 - size : v10;
      i11 = v11 >= size ? v11 - size : v11;
    }

    const v2f* tab = ((const v2f*)table) + off;
    v2f t00 = tab[i00];
    v2f t01 = tab[i01];
    v2f t10 = tab[i10];
    v2f t11 = tab[i11];

    float wx0 = 1.0f - frx, wx1 = frx;
    float wy0 = 1.0f - fry, wy1 = fry;
    float w00 = wx0 * wy0, w01 = wx0 * wy1, w10 = wx1 * wy0, w11 = wx1 * wy1;

    // packed interpolation: fp-contract fuses into v_pk_mul/v_pk_fma
    f2[l] = (w00 * t00 + w01 * t01) + (w10 * t10 + w11 * t11);
  }

  // MLP; layer-2 accumulates j-pairs in float2 lanes (out2[k] holds the
  // partial sums for even/odd j). wc is linear in the output -> applied once
  // at the end, outside the loop.
  v2f out2[8];
  #pragma unroll
  for (int k = 0; k < 8; ++k) out2[k] = (v2f)(0.0f);

  #pragma unroll 1
  for (int j = 0; j < 64; j += 2) {
    const v2f* wr0 = (const v2f*)(w0g + j * 32);        // row j   (16 v2f)
    const v2f* wr1 = (const v2f*)(w0g + j * 32 + 32);   // row j+1

    v2f a0 = wr0[0] * f2[0], b0 = wr0[1] * f2[1];
    v2f a1 = wr1[0] * f2[0], b1 = wr1[1] * f2[1];
    #pragma unroll
    for (int q = 2; q < 16; q += 2) {
      a0 += wr0[q] * f2[q];     b0 += wr0[q + 1] * f2[q + 1];
      a1 += wr1[q] * f2[q];     b1 += wr1[q + 1] * f2[q + 1];
    }
    v2f hv0 = a0 + b0;
    v2f hv1 = a1 + b1;
    v2f s2;
    s2.x = fmaxf(hv0.x + hv0.y, 0.0f);
    s2.y = fmaxf(hv1.x + hv1.y, 0.0f);

    #pragma unroll
    for (int k = 0; k < 8; ++k) {
      v2f w1p = *(const v2f*)(w1g + k * 64 + j);  // uniform s_load_dwordx2
      out2[k] += s2 * w1p;
    }
  }

  float out_acc[8];
  #pragma unroll
  for (int k = 0; k < 8; ++k) out_acc[k] = wc * (out2[k].x + out2[k].y);

  // Quad reduction: sum the 4 corners' weighted outputs.
  #pragma unroll
  for (int k = 0; k < 8; ++k) {
    out_acc[k] += __shfl_xor(out_acc[k], 1, 64);
    out_acc[k] += __shfl_xor(out_acc[k], 2, 64);
  }

  // Each lane of the quad stores output elements (2c, 2c+1); static selects
  // only (dynamic register-array indexing forces scratch).
  const bool cl = (c & 1) != 0;
  const bool ch = (c & 2) != 0;
  float a0 = cl ? out_acc[2] : out_acc[0];
  float a1 = cl ? out_acc[3] : out_acc[1];
  float b0 = cl ? out_acc[6] : out_acc[4];
  float b1 = cl ? out_acc[7] : out_acc[5];
  float2 o;
  o.x = ch ? b0 : a0;
  o.y = ch ? b1 : a1;
  *(float2*)(out + (size_t)p * 8 + 2 * c) = o;
}

extern "C" void kernel_launch(void* const* d_in, const int* in_sizes, int n_in,
                              void* d_out, int out_size, void* d_ws, size_t ws_size,
                              hipStream_t stream) {
  EncParams P;
  double b = exp2(log2(2048.0 / 16.0) / 15.0);
  unsigned off = 0;
  for (int l = 0; l < 16; ++l) {
    double s = 16.0 * pow(b, (double)l) - 1.0;
    int r = (int)ceil(s) + 1;
    unsigned p = (unsigned)(r * r);
    if (p > 524288u) p = 524288u;        // min(HASHMAP_MAX, r*r)
    p = (p + 7u) / 8u * 8u;              // align to 8 entries
    P.lv[l].scale = (float)s;
    P.lv[l].res = (unsigned)r;
    P.lv[l].size = p;
    P.lv[l].offset = off;
    off += p;
  }

  const int N = in_sizes[0] / 2;  // xy is [N,2]
  const int threads_total = N * 4;
  plane_fwd<<<threads_total / 256, 256, 0, stream>>>(
      (const F2*)d_in[0], (const F2*)d_in[1],
      (const float*)d_in[2], (const float*)d_in[3],
      (const int*)d_in[4], (float*)d_out, P);
}

// Round 6
// 495.685 us; speedup vs baseline: 1.9374x; 1.9374x over previous
//
#include <hip/hip_runtime.h>
#include <math.h>

#define PRIME_Y 2654435761u

struct LevelParams { float scale; unsigned res; unsigned size; unsigned offset; };
struct EncParams { LevelParams lv[16]; };

typedef __attribute__((ext_vector_type(8))) short short8;
typedef __attribute__((ext_vector_type(4))) float f32x4;

struct alignas(8) F2 { float x, y; };

// fp32 pair -> packed bf16 (RNE), low = a, high = b
__device__ inline unsigned bf2pack(float a, float b) {
  unsigned ua = __float_as_uint(a);
  unsigned ub = __float_as_uint(b);
  ua = (ua + 0x7FFFu + ((ua >> 16) & 1u)) >> 16;
  ub = (ub + 0x7FFFu + ((ub >> 16) & 1u)) & 0xFFFF0000u;
  return ua | ub;
}

// LDS map (bytes):
//   [0,5120)        sW0  bf16 [64 rows][32] row stride 80
//   [5120,7424)     sW1  bf16 [16 rows][64] row stride 144 (rows 8..15 zero)
//   [7424,44288)    per-wave region, 9216 B each: F bf16 [64][32] stride 80,
//                   then overwritten by reluH bf16 [64][64] stride 144
//                   (in-order DS within a wave makes the union safe)
#define SMEM_BYTES 44288

__global__ __launch_bounds__(256) void plane_fwd(
    const F2* __restrict__ xy,
    const F2* __restrict__ table,
    const float* __restrict__ w0g,
    const float* __restrict__ w1g,
    const int* __restrict__ boundp,
    float* __restrict__ out,
    EncParams P)
{
  __shared__ __align__(16) char smem[SMEM_BYTES];
  const int t = threadIdx.x;
  const int L = t & 63;         // lane in wave
  const int w = t >> 6;         // wave in block
  const int r16 = L & 15;
  const int g = L >> 4;

  // ---- stage W0 (bf16, stride 80) ----
  {
    const float4* s = (const float4*)w0g;     // 512 float4 = 2048 floats
    float4 a = s[t * 2], b = s[t * 2 + 1];    // elems 8t..8t+7 = row t>>2, col 8(t&3)
    uint4 pk = make_uint4(bf2pack(a.x, a.y), bf2pack(a.z, a.w),
                          bf2pack(b.x, b.y), bf2pack(b.z, b.w));
    *(uint4*)(smem + (t >> 2) * 80 + (t & 3) * 16) = pk;
  }
  // ---- stage W1 (bf16, [16][64] stride 144, rows 8..15 = 0) ----
  {
    int row = t >> 4;            // 0..15 (uniform per wave)
    int col = (t & 15) * 4;      // 0..60
    float c0 = 0.f, c1 = 0.f, c2 = 0.f, c3 = 0.f;
    if (row < 8) {
      float4 wv = *(const float4*)(w1g + row * 64 + col);
      c0 = wv.x; c1 = wv.y; c2 = wv.z; c3 = wv.w;
    }
    *(uint2*)(smem + 5120 + row * 144 + col * 2) =
        make_uint2(bf2pack(c0, c1), bf2pack(c2, c3));
  }

  char* sFH = smem + 7424 + w * 9216;   // this wave's F/H region

  // ---- hashgrid encode (fp32, same as R4) ----
  const int gid = blockIdx.x * 256 + t;
  const int p = gid >> 2;
  const int c = t & 3;
  F2 pxy = xy[p];

  int braw = boundp[0];
  float bf = (braw > 0x00800000) ? __int_as_float(braw) : (float)braw;
  float inv2b = 0.5f / bf;
  float xn = (pxy.x + bf) * inv2b;
  float yn = (pxy.y + bf) * inv2b;

  float cx  = fminf(fmaxf(xn * 2048.0f - 0.5f, 0.0f), 2047.0f);
  float cyv = fminf(fmaxf(yn * 2048.0f - 0.5f, 0.0f), 2047.0f);
  float cx0 = floorf(cx), cy0 = floorf(cyv);
  float u = cx - cx0, v = cyv - cy0;
  float cx1 = fminf(cx0 + 1.0f, 2047.0f);
  float cy1 = fminf(cy0 + 1.0f, 2047.0f);

  const float cxc = (c & 1) ? cx1 : cx0;
  const float cyc = (c & 2) ? cy1 : cy0;
  const float wc = ((c & 1) ? u : 1.0f - u) * ((c & 2) ? v : 1.0f - v);

  const float K = 1.0f / 2048.0f;
  const float gx = (cxc + 0.5f) * K;
  const float gy = (cyc + 0.5f) * K;

  unsigned fw[16];

  #pragma unroll
  for (int l = 0; l < 16; ++l) {
    const float scale   = P.lv[l].scale;
    const unsigned res  = P.lv[l].res;
    const unsigned size = P.lv[l].size;
    const unsigned off  = P.lv[l].offset;
    const bool hashed = (res * res) > size;  // wave-uniform

    float px = fmaf(gx, scale, 0.5f);
    float pgx = floorf(px);
    float frx = px - pgx;
    unsigned ux = (unsigned)pgx;

    float py = fmaf(gy, scale, 0.5f);
    float pgy = floorf(py);
    float fry = py - pgy;
    unsigned uy = (unsigned)pgy;

    unsigned i00, i01, i10, i11;
    if (hashed) {
      const unsigned m = size - 1u;   // hashed levels: size == 2^19
      unsigned hy0 = uy * PRIME_Y;
      unsigned hy1 = (uy + 1u) * PRIME_Y;
      i00 = (ux ^ hy0) & m;
      i01 = (ux ^ hy1) & m;
      i10 = ((ux + 1u) ^ hy0) & m;
      i11 = ((ux + 1u) ^ hy1) & m;
    } else {
      unsigned b0 = uy * res, b1 = b0 + res;
      unsigned v00 = ux + b0,      v01 = ux + b1;
      unsigned v10 = ux + 1u + b0, v11 = ux + 1u + b1;
      i00 = v00 >= size ? v00 - size : v00;
      i01 = v01 >= size ? v01 - size : v01;
      i10 = v10 >= size ? v10 - size : v10;
      i11 = v11 >= size ? v11 - size : v11;
    }

    F2 t00 = table[off + i00];
    F2 t01 = table[off + i01];
    F2 t10 = table[off + i10];
    F2 t11 = table[off + i11];

    float wx0 = 1.0f - frx, wx1 = frx;
    float wy0 = 1.0f - fry, wy1 = fry;
    float w00 = wx0 * wy0, w01 = wx0 * wy1, w10 = wx1 * wy0, w11 = wx1 * wy1;

    float fx = w00 * t00.x + w01 * t01.x + w10 * t10.x + w11 * t11.x;
    float fy = w00 * t00.y + w01 * t01.y + w10 * t10.y + w11 * t11.y;
    fw[l] = bf2pack(fx, fy);
  }

  // write this lane's feature row (32 bf16 = 64 B) into sF
  *(uint4*)(sFH + L * 80 +  0) = make_uint4(fw[0],  fw[1],  fw[2],  fw[3]);
  *(uint4*)(sFH + L * 80 + 16) = make_uint4(fw[4],  fw[5],  fw[6],  fw[7]);
  *(uint4*)(sFH + L * 80 + 32) = make_uint4(fw[8],  fw[9],  fw[10], fw[11]);
  *(uint4*)(sFH + L * 80 + 48) = make_uint4(fw[12], fw[13], fw[14], fw[15]);

  __syncthreads();

  // ---- layer 1: Ht[j][m] = W0 . F^T  (A = W0 rows j, B = F rows m) ----
  short8 afr[4], bfr[4];
  #pragma unroll
  for (int b = 0; b < 4; ++b)
    bfr[b] = *(const short8*)(sFH + (16 * b + r16) * 80 + g * 16);
  #pragma unroll
  for (int a = 0; a < 4; ++a)
    afr[a] = *(const short8*)(smem + (16 * a + r16) * 80 + g * 16);

  f32x4 acc[4][4];
  #pragma unroll
  for (int a = 0; a < 4; ++a)
    #pragma unroll
    for (int b = 0; b < 4; ++b)
      acc[a][b] = (f32x4){0.f, 0.f, 0.f, 0.f};

  #pragma unroll
  for (int a = 0; a < 4; ++a)
    #pragma unroll
    for (int b = 0; b < 4; ++b)
      acc[a][b] = __builtin_amdgcn_mfma_f32_16x16x32_bf16(
          afr[a], bfr[b], acc[a][b], 0, 0, 0);

  // relu + bf16, write reluH[m][j] (row m, stride 144) -- j = 16a + 4g + r
  #pragma unroll
  for (int a = 0; a < 4; ++a)
    #pragma unroll
    for (int b = 0; b < 4; ++b) {
      f32x4 h = acc[a][b];
      float h0 = fmaxf(h.x, 0.f), h1 = fmaxf(h.y, 0.f);
      float h2 = fmaxf(h.z, 0.f), h3 = fmaxf(h.w, 0.f);
      *(uint2*)(sFH + (16 * b + r16) * 144 + a * 32 + g * 8) =
          make_uint2(bf2pack(h0, h1), bf2pack(h2, h3));
    }

  __syncthreads();

  // ---- layer 2: O^T[o][m] = W1 . reluH^T  (A = W1 rows o, B = reluH rows m) ----
  f32x4 oacc[4];
  #pragma unroll
  for (int b = 0; b < 4; ++b) oacc[b] = (f32x4){0.f, 0.f, 0.f, 0.f};

  #pragma unroll
  for (int ks = 0; ks < 2; ++ks) {
    short8 a2 = *(const short8*)(smem + 5120 + r16 * 144 + ks * 64 + g * 16);
    #pragma unroll
    for (int b = 0; b < 4; ++b) {
      short8 b2 = *(const short8*)(sFH + (16 * b + r16) * 144 + ks * 64 + g * 16);
      oacc[b] = __builtin_amdgcn_mfma_f32_16x16x32_bf16(a2, b2, oacc[b], 0, 0, 0);
    }
  }

  // ---- blend corners (scale by wc of row m, sum over quad) and store ----
  #pragma unroll
  for (int b = 0; b < 4; ++b) {
    float wcm = __shfl(wc, 16 * b + r16, 64);   // wc of corner-row m
    float v0 = oacc[b].x * wcm;
    float v1 = oacc[b].y * wcm;
    float v2 = oacc[b].z * wcm;
    float v3 = oacc[b].w * wcm;
    v0 += __shfl_xor(v0, 1, 64); v0 += __shfl_xor(v0, 2, 64);
    v1 += __shfl_xor(v1, 1, 64); v1 += __shfl_xor(v1, 2, 64);
    v2 += __shfl_xor(v2, 1, 64); v2 += __shfl_xor(v2, 2, 64);
    v3 += __shfl_xor(v3, 1, 64); v3 += __shfl_xor(v3, 2, 64);
    if ((L & 3) == 0 && g < 2) {
      int pt = blockIdx.x * 64 + w * 16 + 4 * b + (r16 >> 2);
      *(f32x4*)(out + (size_t)pt * 8 + 4 * g) = (f32x4){v0, v1, v2, v3};
    }
  }
}

extern "C" void kernel_launch(void* const* d_in, const int* in_sizes, int n_in,
                              void* d_out, int out_size, void* d_ws, size_t ws_size,
                              hipStream_t stream) {
  EncParams P;
  double b = exp2(log2(2048.0 / 16.0) / 15.0);
  unsigned off = 0;
  for (int l = 0; l < 16; ++l) {
    double s = 16.0 * pow(b, (double)l) - 1.0;
    int r = (int)ceil(s) + 1;
    unsigned p = (unsigned)(r * r);
    if (p > 524288u) p = 524288u;        // min(HASHMAP_MAX, r*r)
    p = (p + 7u) / 8u * 8u;              // align to 8 entries
    P.lv[l].scale = (float)s;
    P.lv[l].res = (unsigned)r;
    P.lv[l].size = p;
    P.lv[l].offset = off;
    off += p;
  }

  const int N = in_sizes[0] / 2;  // xy is [N,2]
  plane_fwd<<<N / 64, 256, 0, stream>>>(
      (const F2*)d_in[0], (const F2*)d_in[1],
      (const float*)d_in[2], (const float*)d_in[3],
      (const int*)d_in[4], (float*)d_out, P);
}